// Round 1
// baseline (506.491 us; speedup 1.0000x reference)
//
#include <hip/hip_runtime.h>
#include <hip/hip_bf16.h>
#include <cstdint>

typedef float f32x4 __attribute__((ext_vector_type(4)));
typedef short short8v __attribute__((ext_vector_type(8)));

#define ATT 256
#define D_IN 512

static __device__ __forceinline__ unsigned short f2bf(float x) {
    return __builtin_bit_cast(unsigned short, __float2bfloat16(x));
}
static __device__ __forceinline__ float bf2f(unsigned short us) {
    return __builtin_bit_cast(float, (uint32_t)us << 16);
}

// ---------------------------------------------------------------------------
// Pre-kernel: W [512][256] fp32 -> bf16 in B-fragment order:
//   o = ((ks*16 + nt)*64 + lane)*8 + j  holds  W[ks*32 + hi*8 + j][nt*16 + lo]
// ---------------------------------------------------------------------------
__global__ void wconv_kernel(const float* __restrict__ W, unsigned short* __restrict__ Wf) {
    int o = blockIdx.x * 256 + threadIdx.x;      // 0 .. 131071
    int j  = o & 7;
    int ln = (o >> 3) & 63;
    int nt = (o >> 9) & 15;
    int ks = o >> 13;
    int hi = ln >> 4, lo = ln & 15;
    int k = ks * 32 + hi * 8 + j;
    int c = nt * 16 + lo;
    Wf[o] = f2bf(W[k * ATT + c]);
}

// ---------------------------------------------------------------------------
// Main kernel: 256 threads = 4 waves; block handles 16 samples = 64 rows.
// ---------------------------------------------------------------------------
__global__ __launch_bounds__(256) void att_main(
    const float* __restrict__ X, const unsigned short* __restrict__ Wf,
    const float* __restrict__ bb, const float* __restrict__ uu,
    float* __restrict__ out, float* __restrict__ alph)
{
    __shared__ __align__(16) unsigned short Xs[64 * 512];   // 64 KB, swizzled bf16
    __shared__ __align__(16) unsigned short Ws[16 * 512];   // 16 KB chunk (32k x 256c)

    const int tid  = threadIdx.x;
    const int wid  = tid >> 6;
    const int lane = tid & 63;
    const int lo   = lane & 15, hi = lane >> 4;
    const int64_t rowbase = (int64_t)blockIdx.x * 64;       // global row = n*4+t

    // ---- stage X: 64 rows x 512 fp32 -> bf16 LDS with XOR swizzle ----
    {
        const float4* Xg = (const float4*)(X + rowbase * D_IN);
        #pragma unroll
        for (int it = 0; it < 32; ++it) {
            int idx = tid + it * 256;               // 0..8191
            int row = idx >> 7, c4 = idx & 127;
            float4 v = Xg[row * 128 + c4];
            ushort4 p;
            p.x = f2bf(v.x); p.y = f2bf(v.y); p.z = f2bf(v.z); p.w = f2bf(v.w);
            int boff = (row * 1024 + c4 * 8) ^ ((row & 7) << 4);
            *(ushort4*)((char*)Xs + boff) = p;
        }
    }

    // ---- MFMA main loop over K ----
    f32x4 acc[16];
    #pragma unroll
    for (int i = 0; i < 16; ++i) acc[i] = (f32x4){0.f, 0.f, 0.f, 0.f};

    const int myrow = wid * 16 + lo;               // LDS row used as A-row
    for (int ks = 0; ks < 16; ++ks) {
        __syncthreads();                           // prev compute done
        {   // stage 16KB W chunk (linear, coalesced: layout already frag-order)
            const short8v* src = (const short8v*)(Wf + ks * 8192);
            short8v* dst = (short8v*)Ws;
            #pragma unroll
            for (int it = 0; it < 4; ++it) dst[tid + it * 256] = src[tid + it * 256];
        }
        __syncthreads();                           // chunk (and Xs on ks==0) visible

        int aoff = (myrow * 1024 + ks * 64 + hi * 16) ^ ((myrow & 7) << 4);
        short8v a = *(const short8v*)((const char*)Xs + aoff);
        #pragma unroll
        for (int nt = 0; nt < 16; ++nt) {
            short8v bfr = *(const short8v*)(Ws + (nt * 64 + lane) * 8);
            acc[nt] = __builtin_amdgcn_mfma_f32_16x16x32_bf16(a, bfr, acc[nt], 0, 0, 0);
        }
    }

    // ---- epilogue: tanh, u-dot, 16-lane butterfly, softmax, weighted sum ----
    float vu[4] = {0.f, 0.f, 0.f, 0.f};
    #pragma unroll
    for (int nt = 0; nt < 16; ++nt) {
        int c = nt * 16 + lo;
        float bc = bb[c], uc = uu[c];
        #pragma unroll
        for (int r = 0; r < 4; ++r) {
            float v = tanhf(acc[nt][r] + bc);
            vu[r] += v * uc;
        }
    }
    #pragma unroll
    for (int m = 1; m < 16; m <<= 1) {
        #pragma unroll
        for (int r = 0; r < 4; ++r) vu[r] += __shfl_xor(vu[r], m, 64);
    }
    // lane-local softmax over the 4 t's (rows 4*hi + r of this wave's tile)
    float mx = fmaxf(fmaxf(vu[0], vu[1]), fmaxf(vu[2], vu[3]));
    float e0 = __expf(vu[0] - mx), e1 = __expf(vu[1] - mx);
    float e2 = __expf(vu[2] - mx), e3 = __expf(vu[3] - mx);
    float inv = 1.f / (e0 + e1 + e2 + e3);
    float a0 = e0 * inv, a1 = e1 * inv, a2 = e2 * inv, a3 = e3 * inv;

    const int sloc = wid * 4 + hi;                 // local sample 0..15
    const int64_t s = (int64_t)blockIdx.x * 16 + sloc;

    float* outp = out + s * D_IN;
    #pragma unroll
    for (int i = 0; i < 8; ++i) {
        int d4 = i * 16 + lo;                      // float4 index 0..127
        float ox = 0.f, oy = 0.f, oz = 0.f, ow = 0.f;
        #pragma unroll
        for (int r = 0; r < 4; ++r) {
            int row = sloc * 4 + r;
            int boff = (row * 1024 + d4 * 8) ^ ((row & 7) << 4);
            ushort4 xq = *(const ushort4*)((const char*)Xs + boff);
            float ar = (r == 0) ? a0 : (r == 1) ? a1 : (r == 2) ? a2 : a3;
            ox += ar * bf2f(xq.x);
            oy += ar * bf2f(xq.y);
            oz += ar * bf2f(xq.z);
            ow += ar * bf2f(xq.w);
        }
        float4 o4; o4.x = ox; o4.y = oy; o4.z = oz; o4.w = ow;
        *(float4*)(outp + d4 * 4) = o4;
    }
    if (lo < 4) {
        float av = (lo == 0) ? a0 : (lo == 1) ? a1 : (lo == 2) ? a2 : a3;
        alph[s * 4 + lo] = av;
    }
}

// ---------------------------------------------------------------------------
// Fallback (only if d_ws is too small): plain fp32, 1 block per sample.
// ---------------------------------------------------------------------------
__global__ void att_fallback(const float* __restrict__ X, const float* __restrict__ W,
                             const float* __restrict__ bb, const float* __restrict__ uu,
                             float* __restrict__ out, float* __restrict__ alph)
{
    const int s = blockIdx.x;
    const int tid = threadIdx.x;                   // 256 threads
    __shared__ float Xs[2048];
    __shared__ float red[4][4];
    __shared__ float alsh[4];
    for (int i = tid; i < 2048; i += 256) Xs[i] = X[(size_t)s * 2048 + i];
    __syncthreads();
    float vus[4];
    const int a = tid;
    for (int t = 0; t < 4; ++t) {
        float acc = bb[a];
        for (int d = 0; d < 512; ++d) acc += Xs[t * 512 + d] * W[d * 256 + a];
        vus[t] = tanhf(acc) * uu[a];
    }
    const int wid = tid >> 6, lane = tid & 63;
    for (int t = 0; t < 4; ++t) {
        float v = vus[t];
        for (int m = 1; m < 64; m <<= 1) v += __shfl_xor(v, m, 64);
        if (lane == 0) red[t][wid] = v;
    }
    __syncthreads();
    if (tid == 0) {
        float vv[4];
        for (int t = 0; t < 4; ++t) vv[t] = red[t][0] + red[t][1] + red[t][2] + red[t][3];
        float mx = fmaxf(fmaxf(vv[0], vv[1]), fmaxf(vv[2], vv[3]));
        float e[4], ssum = 0.f;
        for (int t = 0; t < 4; ++t) { e[t] = expf(vv[t] - mx); ssum += e[t]; }
        for (int t = 0; t < 4; ++t) {
            float av = e[t] / ssum;
            alsh[t] = av;
            alph[(size_t)s * 4 + t] = av;
        }
    }
    __syncthreads();
    for (int d = tid; d < 512; d += 256) {
        float o = 0.f;
        for (int t = 0; t < 4; ++t) o += alsh[t] * Xs[t * 512 + d];
        out[(size_t)s * 512 + d] = o;
    }
}

// ---------------------------------------------------------------------------
extern "C" void kernel_launch(void* const* d_in, const int* in_sizes, int n_in,
                              void* d_out, int out_size, void* d_ws, size_t ws_size,
                              hipStream_t stream) {
    const float* X = (const float*)d_in[0];
    const float* W = (const float*)d_in[1];
    const float* b = (const float*)d_in[2];
    const float* u = (const float*)d_in[3];
    float* out = (float*)d_out;
    const int N = in_sizes[0] / (4 * D_IN);
    float* alph = out + (size_t)N * D_IN;

    if (ws_size >= (size_t)D_IN * ATT * sizeof(unsigned short) && (N % 16) == 0) {
        unsigned short* Wf = (unsigned short*)d_ws;
        wconv_kernel<<<(D_IN * ATT) / 256, 256, 0, stream>>>(W, Wf);
        att_main<<<N / 16, 256, 0, stream>>>(X, Wf, b, u, out, alph);
    } else {
        att_fallback<<<N, 256, 0, stream>>>(X, W, b, u, out, alph);
    }
}